// Round 1
// baseline (429.474 us; speedup 1.0000x reference)
//
#include <hip/hip_runtime.h>
#include <hip/hip_bf16.h>

// Problem: V_logits (B=4, C=3, K=128, H=256, W=256) f32.
// Per pixel (b,h,w): scan depth k for first k where argmax_c(logit) != 0.
// visible_depth = that k (or K-1 if none). visible_class = argmax there (0 if none).
// visible_probs = softmax_c(logits at visible_depth).
// Outputs flat f32: [ visible_class (B*H*W) | visible_probs (B*C*H*W) ].
//
// Key insight: argmax(softmax)==argmax(logits); softmax needed only at ONE k
// per pixel. Hit prob per k is 2/3 -> wave exits after ~4 iterations, so we
// touch ~15 MB of the 403 MB input. Latency-bound, not BW-bound.

constexpr int Bn = 4;
constexpr int Cn = 3;
constexpr int Kn = 128;
constexpr int Hn = 256;
constexpr int Wn = 256;
constexpr int HW = Hn * Wn;            // 65536
constexpr int NPIX = Bn * HW;          // 262144

__global__ __launch_bounds__(256) void first_hit_kernel(
    const float* __restrict__ V, float* __restrict__ out) {
    int idx = blockIdx.x * blockDim.x + threadIdx.x;
    if (idx >= NPIX) return;

    int b  = idx >> 16;        // / HW (HW = 65536)
    int hw = idx & (HW - 1);

    const size_t strideK = (size_t)HW;              // 65536 elems
    const size_t strideC = (size_t)Kn * HW;         // 8388608 elems
    const float* base = V + (size_t)b * Cn * strideC + (size_t)hw;

    float x0 = 0.f, x1 = 0.f, x2 = 0.f;
    #pragma unroll 1
    for (int k = 0; k < Kn; ++k) {
        size_t off = (size_t)k * strideK;
        x0 = base[off];
        x1 = base[off + strideC];
        x2 = base[off + 2 * strideC];
        // first-occurrence argmax over 3 (strict > keeps earliest index)
        if (x1 > x0 || x2 > x0) break;   // class != 0 -> hit
        // no hit at this k; if k==Kn-1 loop ends and x* hold k=K-1 values,
        // where argmax is 0 (BG) — exactly the no-hit semantics.
    }

    // class at the selected depth (hit depth, or K-1 where argmax==0 anyway)
    int   cls = 0;
    float m   = x0;
    if (x1 > m) { cls = 1; m = x1; }
    if (x2 > m) { cls = 2; m = x2; }

    // softmax over the 3 logits
    float e0 = __expf(x0 - m);
    float e1 = __expf(x1 - m);
    float e2 = __expf(x2 - m);
    float inv = 1.0f / (e0 + e1 + e2);

    // outputs: [class: NPIX floats][probs: (B,C,H,W) floats]
    out[idx] = (float)cls;
    float* probs = out + NPIX;
    size_t pbase = (size_t)b * Cn * HW + (size_t)hw;
    probs[pbase]            = e0 * inv;
    probs[pbase + HW]       = e1 * inv;
    probs[pbase + 2 * HW]   = e2 * inv;
}

extern "C" void kernel_launch(void* const* d_in, const int* in_sizes, int n_in,
                              void* d_out, int out_size, void* d_ws, size_t ws_size,
                              hipStream_t stream) {
    const float* V = (const float*)d_in[0];
    float* out = (float*)d_out;
    int threads = 256;
    int blocks = (NPIX + threads - 1) / threads;   // 1024
    first_hit_kernel<<<blocks, threads, 0, stream>>>(V, out);
}